// Round 1
// baseline (71.406 us; speedup 1.0000x reference)
//
#include <hip/hip_runtime.h>

constexpr int NQ = 7;
constexpr int NL = 4;
constexpr int NGATES = NL * NQ;   // 28
constexpr int NCLS = 22;

// One wave = one batch element. Lane holds amplitudes i = 2*lane (a0) and 2*lane+1 (a1).
// Qubit q lives at bit (6-q) of the amplitude index:
//   q = 6  -> bit 0 = r (thread-local pair a0/a1)
//   q <= 5 -> lane bit (5-q)  (pair via __shfl_xor mask 1<<(5-q))
__global__ __launch_bounds__(256) void reupload_kernel(
    const float* __restrict__ x,       // (B,7)
    const float* __restrict__ wts,     // (4,7,3)
    const float* __restrict__ fc1_w,   // (32,7)
    const float* __restrict__ fc1_b,   // (32,)
    const float* __restrict__ fc2_w,   // (22,32)
    const float* __restrict__ fc2_b,   // (22,)
    float* __restrict__ out,           // (B,22)
    int B)
{
    // --- per-block: precompute the 28 batch-independent Rot matrices into LDS ---
    __shared__ float rotU[NGATES * 8];
    {
        int tid = threadIdx.x;
        if (tid < NGATES) {
            float phi = wts[tid*3+0], th = wts[tid*3+1], om = wts[tid*3+2];
            float ct = __cosf(0.5f*th), st = __sinf(0.5f*th);
            float ap = 0.5f*(phi+om),  am = 0.5f*(phi-om);
            float cp = __cosf(ap), sp = __sinf(ap);
            float cm = __cosf(am), sm = __sinf(am);
            float* u = &rotU[tid*8];
            // ep = cp - i*sp ; em = cm - i*sm
            u[0] =  cp*ct; u[1] = -sp*ct;   // u00 = ep*ct
            u[2] = -cm*st; u[3] = -sm*st;   // u01 = -conj(em)*st
            u[4] =  cm*st; u[5] = -sm*st;   // u10 = em*st
            u[6] =  cp*ct; u[7] =  sp*ct;   // u11 = conj(ep)*ct
        }
    }
    __syncthreads();

    const int lane = threadIdx.x & 63;
    const int b = blockIdx.x * (blockDim.x >> 6) + (threadIdx.x >> 6);
    if (b >= B) return;   // b is wave-uniform

    // RX coefficients (batch-dependent, wave-uniform)
    float c[NQ], s[NQ];
    #pragma unroll
    for (int q = 0; q < NQ; ++q) {
        float h = 0.5f * x[b*NQ + q];
        c[q] = __cosf(h); s[q] = __sinf(h);
    }

    // state |0...0>
    float a0r = (lane == 0) ? 1.f : 0.f, a0i = 0.f, a1r = 0.f, a1i = 0.f;

    #pragma unroll
    for (int l = 0; l < NL; ++l) {
        // ---------- RX(x[q]) on every qubit ----------
        #pragma unroll
        for (int q = 0; q < 6; ++q) {
            const int m = 1 << (5 - q);
            float w0r = __shfl_xor(a0r, m), w0i = __shfl_xor(a0i, m);
            float w1r = __shfl_xor(a1r, m), w1i = __shfl_xor(a1i, m);
            const float cq = c[q], sq = s[q];
            // new = c*v - i*s*w  (same formula both sides of the pair)
            float n0r = cq*a0r + sq*w0i, n0i = cq*a0i - sq*w0r;
            float n1r = cq*a1r + sq*w1i, n1i = cq*a1i - sq*w1r;
            a0r = n0r; a0i = n0i; a1r = n1r; a1i = n1i;
        }
        {   // q = 6, thread-local
            const float cq = c[6], sq = s[6];
            float n0r = cq*a0r + sq*a1i, n0i = cq*a0i - sq*a1r;
            float n1r = cq*a1r + sq*a0i, n1i = cq*a1i - sq*a0r;
            a0r = n0r; a0i = n0i; a1r = n1r; a1i = n1i;
        }

        // ---------- Rot(phi,theta,omega) on every qubit ----------
        #pragma unroll
        for (int q = 0; q < 6; ++q) {
            const float4* up = (const float4*)&rotU[(l*NQ + q)*8];
            const float4 uA = up[0];   // u00r,u00i,u01r,u01i
            const float4 uB = up[1];   // u10r,u10i,u11r,u11i
            const int m = 1 << (5 - q);
            const bool hi = (lane & m) != 0;
            // bit==0: new = u00*v + u01*w ; bit==1: new = u11*v + u10*w
            const float cvr = hi ? uB.z : uA.x, cvi = hi ? uB.w : uA.y;
            const float cwr = hi ? uB.x : uA.z, cwi = hi ? uB.y : uA.w;
            float w0r = __shfl_xor(a0r, m), w0i = __shfl_xor(a0i, m);
            float w1r = __shfl_xor(a1r, m), w1i = __shfl_xor(a1i, m);
            float n0r = cvr*a0r - cvi*a0i + cwr*w0r - cwi*w0i;
            float n0i = cvr*a0i + cvi*a0r + cwr*w0i + cwi*w0r;
            float n1r = cvr*a1r - cvi*a1i + cwr*w1r - cwi*w1i;
            float n1i = cvr*a1i + cvi*a1r + cwr*w1i + cwi*w1r;
            a0r = n0r; a0i = n0i; a1r = n1r; a1i = n1i;
        }
        {   // q = 6, thread-local: a0 has bit 0, a1 has bit 1
            const float4* up = (const float4*)&rotU[(l*NQ + 6)*8];
            const float4 uA = up[0], uB = up[1];
            float n0r = uA.x*a0r - uA.y*a0i + uA.z*a1r - uA.w*a1i;
            float n0i = uA.x*a0i + uA.y*a0r + uA.z*a1i + uA.w*a1r;
            float n1r = uB.x*a0r - uB.y*a0i + uB.z*a1r - uB.w*a1i;
            float n1i = uB.x*a0i + uB.y*a0r + uB.z*a1i + uB.w*a1r;
            a0r = n0r; a0i = n0i; a1r = n1r; a1i = n1i;
        }

        // ---------- CNOT ring: CNOT(q, q+1 mod 7), q = 0..6 in order ----------
        #pragma unroll
        for (int q = 0; q < 5; ++q) {
            const int mt = 1 << (4 - q);   // target lane bit
            const int mc = 1 << (5 - q);   // control lane bit
            float w0r = __shfl_xor(a0r, mt), w0i = __shfl_xor(a0i, mt);
            float w1r = __shfl_xor(a1r, mt), w1i = __shfl_xor(a1i, mt);
            const bool ctrl = (lane & mc) != 0;
            a0r = ctrl ? w0r : a0r; a0i = ctrl ? w0i : a0i;
            a1r = ctrl ? w1r : a1r; a1i = ctrl ? w1i : a1i;
        }
        {   // q = 5: control lane bit 0, target is r -> local swap where ctrl
            const bool ctrl = (lane & 1) != 0;
            float t0r = a0r, t0i = a0i;
            a0r = ctrl ? a1r : a0r; a0i = ctrl ? a1i : a0i;
            a1r = ctrl ? t0r : a1r; a1i = ctrl ? t0i : a1i;
        }
        {   // q = 6: control r=1, target lane bit 5 -> swap a1 across lane^32
            a1r = __shfl_xor(a1r, 32);
            a1i = __shfl_xor(a1i, 32);
        }
    }

    // ---------- <Z_j> measurement ----------
    const float p0 = a0r*a0r + a0i*a0i;
    const float p1 = a1r*a1r + a1i*a1i;
    const float t  = p0 + p1;
    float z[NQ];
    #pragma unroll
    for (int j = 0; j < 6; ++j) z[j] = (lane & (1 << (5 - j))) ? -t : t;
    z[6] = p0 - p1;
    #pragma unroll
    for (int m = 1; m < 64; m <<= 1) {
        #pragma unroll
        for (int j = 0; j < NQ; ++j) z[j] += __shfl_xor(z[j], m);
    }
    // every lane now holds q_out[b, 0..6]

    // ---------- MLP: 7 -> 32 (relu) -> 22 ----------
    const int mrow = lane & 31;            // duplicate rows on upper half: keeps all shfl sources active
    float acc1 = fc1_b[mrow];
    #pragma unroll
    for (int j = 0; j < NQ; ++j) acc1 += z[j] * fc1_w[mrow*NQ + j];
    const float h = fmaxf(acc1, 0.f);

    const int k = (lane < NCLS) ? lane : 0;
    float acc2 = fc2_b[k];
    float wrow[32];
    const float4* w4 = (const float4*)(fc2_w + k*32);
    #pragma unroll
    for (int i = 0; i < 8; ++i) {
        float4 v = w4[i];
        wrow[i*4+0] = v.x; wrow[i*4+1] = v.y; wrow[i*4+2] = v.z; wrow[i*4+3] = v.w;
    }
    #pragma unroll
    for (int m = 0; m < 32; ++m) {
        float hm = __shfl(h, m);
        acc2 += hm * wrow[m];
    }
    if (lane < NCLS) out[b*NCLS + lane] = acc2;
}

extern "C" void kernel_launch(void* const* d_in, const int* in_sizes, int n_in,
                              void* d_out, int out_size, void* d_ws, size_t ws_size,
                              hipStream_t stream) {
    const float* x     = (const float*)d_in[0];
    const float* wts   = (const float*)d_in[1];
    const float* fc1_w = (const float*)d_in[2];
    const float* fc1_b = (const float*)d_in[3];
    const float* fc2_w = (const float*)d_in[4];
    const float* fc2_b = (const float*)d_in[5];
    float* out = (float*)d_out;

    const int B = in_sizes[0] / NQ;
    const int wavesPerBlock = 4;           // 256 threads
    const int grid = (B + wavesPerBlock - 1) / wavesPerBlock;
    reupload_kernel<<<grid, 256, 0, stream>>>(x, wts, fc1_w, fc1_b, fc2_w, fc2_b, out, B);
}

// Round 4
// 38.913 us; speedup vs baseline: 1.8350x; 1.8350x over previous
//
#include <hip/hip_runtime.h>

constexpr int NQ = 7;
constexpr int NL = 4;
constexpr int NG = NL * NQ;   // 28
constexpr int NCLS = 22;

// ---------------- cross-lane primitives ----------------
// masks 1,2 -> DPP quad_perm builtin (VALU pipe); masks 4,8,16 -> ds_swizzle
// builtin with guide-listed XOR encodings; mask 32 -> __shfl_xor (R1-proven).
// NO inline-asm value ops (R2/R3 bug: "+v" asm operands with equal values can
// be register-coalesced, turning permlane*_swap into a self-swap).

template<int CTRL>
__device__ __forceinline__ float fdpp(float v) {
    return __int_as_float(__builtin_amdgcn_mov_dpp(__float_as_int(v), CTRL, 0xF, 0xF, true));
}
template<int OFF>
__device__ __forceinline__ float fswz(float v) {
    return __int_as_float(__builtin_amdgcn_ds_swizzle(__float_as_int(v), OFF));
}

template<int M>
__device__ __forceinline__ float xorl(float v) {
    if      constexpr (M == 1)  return fdpp<0xB1>(v);      // quad_perm [1,0,3,2]
    else if constexpr (M == 2)  return fdpp<0x4E>(v);      // quad_perm [2,3,0,1]
    else if constexpr (M == 4)  return fswz<0x101F>(v);    // xor4  (guide-listed)
    else if constexpr (M == 8)  return fswz<0x201F>(v);    // xor8  (guide-listed)
    else if constexpr (M == 16) return fswz<0x401F>(v);    // xor16 (guide-listed)
    else                        return __shfl_xor(v, 32);  // ds_bpermute, R1-proven
}

// ---------------- fused gate build: U' = U_rot @ RX(c,s) ----------------
// u[8] = {u00r,u00i,u01r,u01i,u10r,u10i,u11r,u11i} (wave-uniform load)
__device__ __forceinline__ void fuse(const float* __restrict__ u, float c, float s,
                                     float4& A, float4& B) {
    A.x = fmaf(c, u[0],  s * u[3]);  A.y = fmaf(c, u[1], -s * u[2]);
    A.z = fmaf(c, u[2],  s * u[1]);  A.w = fmaf(c, u[3], -s * u[0]);
    B.x = fmaf(c, u[4],  s * u[7]);  B.y = fmaf(c, u[5], -s * u[6]);
    B.z = fmaf(c, u[6],  s * u[5]);  B.w = fmaf(c, u[7], -s * u[4]);
}

// general 2x2 on a lane-bit qubit (pair across lane mask M)
template<int M>
__device__ __forceinline__ void gateL(int lane, float4 A, float4 B,
                                      float& a0r, float& a0i, float& a1r, float& a1i) {
    const bool hi = (lane & M) != 0;
    const float avr = hi ? B.z : A.x, avi = hi ? B.w : A.y;   // diag coeff
    const float awr = hi ? B.x : A.z, awi = hi ? B.y : A.w;   // off-diag coeff
    const float w0r = xorl<M>(a0r), w0i = xorl<M>(a0i);
    const float w1r = xorl<M>(a1r), w1i = xorl<M>(a1i);
    float n0r = avr*a0r - avi*a0i + awr*w0r - awi*w0i;
    float n0i = avr*a0i + avi*a0r + awr*w0i + awi*w0r;
    float n1r = avr*a1r - avi*a1i + awr*w1r - awi*w1i;
    float n1i = avr*a1i + avi*a1r + awr*w1i + awi*w1r;
    a0r = n0r; a0i = n0i; a1r = n1r; a1i = n1i;
}

template<int MT, int MC>
__device__ __forceinline__ void cnotL(int lane,
                                      float& a0r, float& a0i, float& a1r, float& a1i) {
    const float w0r = xorl<MT>(a0r), w0i = xorl<MT>(a0i);
    const float w1r = xorl<MT>(a1r), w1i = xorl<MT>(a1i);
    const bool c = (lane & MC) != 0;
    a0r = c ? w0r : a0r;  a0i = c ? w0i : a0i;
    a1r = c ? w1r : a1r;  a1i = c ? w1i : a1i;
}

// ---------------- setup: 28 batch-independent Rot matrices -> d_ws ----------------
__global__ __launch_bounds__(64) void rot_setup(const float* __restrict__ wts,
                                                float* __restrict__ ru) {
    int g = threadIdx.x;
    if (g < NG) {
        float phi = wts[g*3+0], th = wts[g*3+1], om = wts[g*3+2];
        float ct = __cosf(0.5f*th), st = __sinf(0.5f*th);
        float ap = 0.5f*(phi+om),  am = 0.5f*(phi-om);
        float cp = __cosf(ap), sp = __sinf(ap);
        float cm = __cosf(am), sm = __sinf(am);
        float* u = ru + g*8;
        u[0] =  cp*ct; u[1] = -sp*ct;   // u00 = ep*ct        (ep = cp - i sp)
        u[2] = -cm*st; u[3] = -sm*st;   // u01 = -conj(em)*st (em = cm - i sm)
        u[4] =  cm*st; u[5] = -sm*st;   // u10 = em*st
        u[6] =  cp*ct; u[7] =  sp*ct;   // u11 = conj(ep)*ct
    }
}

// ---------------- main kernel: one wave = one batch element ----------------
// lane holds amplitudes 2*lane (a0) and 2*lane+1 (a1); qubit q <-> amp bit (6-q):
// q=6 local pair, q<=5 lane bit (5-q)
__global__ __launch_bounds__(256) void reupload_kernel(
    const float* __restrict__ x,       // (B,7)
    const float* __restrict__ ru,      // (28,8) precomputed Rot matrices
    const float* __restrict__ fc1_w,   // (32,7)
    const float* __restrict__ fc1_b,   // (32,)
    const float* __restrict__ fc2_w,   // (22,32)
    const float* __restrict__ fc2_b,   // (22,)
    float* __restrict__ out,           // (B,22)
    int B)
{
    const int lane = threadIdx.x & 63;
    const int wid  = threadIdx.x >> 6;
    const int b    = blockIdx.x * 4 + wid;
    if (b >= B) return;

    float c[NQ], s[NQ];
    #pragma unroll
    for (int q = 0; q < NQ; ++q) {
        float h = 0.5f * x[b*NQ + q];
        c[q] = __cosf(h); s[q] = __sinf(h);
    }

    float a0r = (lane == 0) ? 1.f : 0.f, a0i = 0.f, a1r = 0.f, a1i = 0.f;

    #pragma unroll
    for (int l = 0; l < NL; ++l) {
        const float* rl = ru + l * (NQ * 8);
        float4 A, Bq;
        // fused Rot·RX per qubit (single-qubit gates on distinct qubits commute,
        // same-qubit order Rot∘RX preserved)
        fuse(rl +  0, c[0], s[0], A, Bq); gateL<32>(lane, A, Bq, a0r, a0i, a1r, a1i);
        fuse(rl +  8, c[1], s[1], A, Bq); gateL<16>(lane, A, Bq, a0r, a0i, a1r, a1i);
        fuse(rl + 16, c[2], s[2], A, Bq); gateL< 8>(lane, A, Bq, a0r, a0i, a1r, a1i);
        fuse(rl + 24, c[3], s[3], A, Bq); gateL< 4>(lane, A, Bq, a0r, a0i, a1r, a1i);
        fuse(rl + 32, c[4], s[4], A, Bq); gateL< 2>(lane, A, Bq, a0r, a0i, a1r, a1i);
        fuse(rl + 40, c[5], s[5], A, Bq); gateL< 1>(lane, A, Bq, a0r, a0i, a1r, a1i);
        {   // q = 6 local: full 2x2 on (a0,a1)
            fuse(rl + 48, c[6], s[6], A, Bq);
            float n0r = A.x*a0r - A.y*a0i + A.z*a1r - A.w*a1i;
            float n0i = A.x*a0i + A.y*a0r + A.z*a1i + A.w*a1r;
            float n1r = Bq.x*a0r - Bq.y*a0i + Bq.z*a1r - Bq.w*a1i;
            float n1i = Bq.x*a0i + Bq.y*a0r + Bq.z*a1i + Bq.w*a1r;
            a0r = n0r; a0i = n0i; a1r = n1r; a1i = n1i;
        }
        // CNOT ring CNOT(q, q+1 mod 7), reference order q=0..6
        cnotL<16,32>(lane, a0r, a0i, a1r, a1i);
        cnotL< 8,16>(lane, a0r, a0i, a1r, a1i);
        cnotL< 4, 8>(lane, a0r, a0i, a1r, a1i);
        cnotL< 2, 4>(lane, a0r, a0i, a1r, a1i);
        cnotL< 1, 2>(lane, a0r, a0i, a1r, a1i);
        {   // q=5: control amp-bit1 (lane bit 0), target local pair swap
            const bool cc = (lane & 1) != 0;
            float t0r = a0r, t0i = a0i;
            a0r = cc ? a1r : a0r; a0i = cc ? a1i : a0i;
            a1r = cc ? t0r : a1r; a1i = cc ? t0i : a1i;
        }
        {   // q=6: control amp-bit0 -> swap a1 across lane^32
            a1r = xorl<32>(a1r);
            a1i = xorl<32>(a1i);
        }
    }

    // ---------- <Z_j> ----------
    const float p0 = a0r*a0r + a0i*a0i;
    const float p1 = a1r*a1r + a1i*a1i;
    const float t  = p0 + p1;
    float z[NQ];
    #pragma unroll
    for (int j = 0; j < 6; ++j) z[j] = (lane & (1 << (5 - j))) ? -t : t;
    z[6] = p0 - p1;
    #pragma unroll
    for (int j = 0; j < NQ; ++j) {
        float v = z[j];
        v += xorl<1>(v);
        v += xorl<2>(v);
        v += xorl<4>(v);
        v += xorl<8>(v);
        v += xorl<16>(v);
        v += xorl<32>(v);
        z[j] = v;   // full sum in every lane
    }

    // ---------- MLP 7 -> 32(relu) -> 22 ----------
    __shared__ __align__(16) float hbuf[4][32];
    const int mrow = lane & 31;
    float acc1 = fc1_b[mrow];
    #pragma unroll
    for (int j = 0; j < NQ; ++j) acc1 = fmaf(z[j], fc1_w[mrow*NQ + j], acc1);
    const float h = fmaxf(acc1, 0.f);
    if (lane < 32) hbuf[wid][lane] = h;
    __builtin_amdgcn_wave_barrier();
    asm volatile("s_waitcnt lgkmcnt(0)" ::: "memory");
    __builtin_amdgcn_sched_barrier(0);

    float hv[32];
    #pragma unroll
    for (int i = 0; i < 8; ++i) {   // broadcast reads: all lanes same address
        float4 v4 = *reinterpret_cast<const float4*>(&hbuf[wid][i*4]);
        hv[i*4+0] = v4.x; hv[i*4+1] = v4.y; hv[i*4+2] = v4.z; hv[i*4+3] = v4.w;
    }
    const int k = (lane < NCLS) ? lane : 0;
    float acc2 = fc2_b[k];
    const float4* w4 = reinterpret_cast<const float4*>(fc2_w + k*32);
    #pragma unroll
    for (int i = 0; i < 8; ++i) {
        float4 wv = w4[i];
        acc2 = fmaf(hv[i*4+0], wv.x, acc2);
        acc2 = fmaf(hv[i*4+1], wv.y, acc2);
        acc2 = fmaf(hv[i*4+2], wv.z, acc2);
        acc2 = fmaf(hv[i*4+3], wv.w, acc2);
    }
    if (lane < NCLS) out[b*NCLS + lane] = acc2;
}

extern "C" void kernel_launch(void* const* d_in, const int* in_sizes, int n_in,
                              void* d_out, int out_size, void* d_ws, size_t ws_size,
                              hipStream_t stream) {
    const float* x     = (const float*)d_in[0];
    const float* wts   = (const float*)d_in[1];
    const float* fc1_w = (const float*)d_in[2];
    const float* fc1_b = (const float*)d_in[3];
    const float* fc2_w = (const float*)d_in[4];
    const float* fc2_b = (const float*)d_in[5];
    float* out = (float*)d_out;
    float* ru  = (float*)d_ws;   // 28*8 floats = 896 B

    rot_setup<<<1, 64, 0, stream>>>(wts, ru);

    const int B = in_sizes[0] / NQ;
    const int grid = (B + 3) / 4;
    reupload_kernel<<<grid, 256, 0, stream>>>(x, ru, fc1_w, fc1_b, fc2_w, fc2_b, out, B);
}